// Round 1
// baseline (1416.600 us; speedup 1.0000x reference)
//
#include <hip/hip_runtime.h>
#include <hip/hip_bf16.h>
#include <math.h>

#define D_MODEL 1024
#define N_HEADS 16
#define D_K 64
#define N_CLASSES 32
#define S_LEN 16
#define BATCH 32
#define T_LEN 512

__device__ inline float4 tanh4(float4 v) {
    return make_float4(tanhf(v.x), tanhf(v.y), tanhf(v.z), tanhf(v.w));
}
__device__ inline float dot4(float4 a, float4 b) {
    return a.x * b.x + a.y * b.y + a.z * b.z + a.w * b.w;
}

// ---------------- SGEMM: C = op(A @ B^T) ----------------
// A: (M,K) row-major, B: (N,K) row-major, C: (M,N) row-major.
// 128x128 tile, BK=16, 256 threads, 8x8 per thread (4+4 split at +64 to keep
// LDS float4 reads 2-way-or-less bank aliased).
__global__ __launch_bounds__(256) void sgemm_bt(
    const float* __restrict__ A, const float* __restrict__ B,
    float* __restrict__ C, int M, int N, int K, int applyTanh)
{
    __shared__ float As[16][132];
    __shared__ float Bs[16][132];
    const int tid = threadIdx.x;
    const int n0 = blockIdx.x * 128;
    const int m0 = blockIdx.y * 128;
    const int tx = tid & 15;        // 0..15
    const int ty = tid >> 4;        // 0..15
    const int lr = tid >> 2;        // 0..63
    const int lk = (tid & 3) << 2;  // 0,4,8,12

    float acc[8][8];
#pragma unroll
    for (int i = 0; i < 8; i++)
#pragma unroll
        for (int j = 0; j < 8; j++) acc[i][j] = 0.f;

    for (int k0 = 0; k0 < K; k0 += 16) {
#pragma unroll
        for (int h = 0; h < 2; h++) {
            const int row = lr + h * 64;
            const int gm = m0 + row;
            float4 v = make_float4(0.f, 0.f, 0.f, 0.f);
            if (gm < M) v = *(const float4*)(A + (size_t)gm * K + k0 + lk);
            As[lk + 0][row] = v.x; As[lk + 1][row] = v.y;
            As[lk + 2][row] = v.z; As[lk + 3][row] = v.w;
        }
#pragma unroll
        for (int h = 0; h < 2; h++) {
            const int row = lr + h * 64;
            const int gn = n0 + row;  // N is always a multiple of 128 here
            float4 v = *(const float4*)(B + (size_t)gn * K + k0 + lk);
            Bs[lk + 0][row] = v.x; Bs[lk + 1][row] = v.y;
            Bs[lk + 2][row] = v.z; Bs[lk + 3][row] = v.w;
        }
        __syncthreads();
#pragma unroll
        for (int k = 0; k < 16; k++) {
            const float4 a0 = *(const float4*)(&As[k][4 * ty]);
            const float4 a1 = *(const float4*)(&As[k][4 * ty + 64]);
            const float4 b0 = *(const float4*)(&Bs[k][4 * tx]);
            const float4 b1 = *(const float4*)(&Bs[k][4 * tx + 64]);
            const float ar[8] = {a0.x, a0.y, a0.z, a0.w, a1.x, a1.y, a1.z, a1.w};
            const float br[8] = {b0.x, b0.y, b0.z, b0.w, b1.x, b1.y, b1.z, b1.w};
#pragma unroll
            for (int i = 0; i < 8; i++)
#pragma unroll
                for (int j = 0; j < 8; j++) acc[i][j] += ar[i] * br[j];
        }
        __syncthreads();
    }

#pragma unroll
    for (int i = 0; i < 8; i++) {
        const int gm = m0 + ((i < 4) ? (4 * ty + i) : (64 + 4 * ty + (i - 4)));
        if (gm < M) {
#pragma unroll
            for (int jh = 0; jh < 2; jh++) {
                const int gn = n0 + 4 * tx + jh * 64;
                float4 v = make_float4(acc[i][jh * 4 + 0], acc[i][jh * 4 + 1],
                                       acc[i][jh * 4 + 2], acc[i][jh * 4 + 3]);
                if (applyTanh) v = tanh4(v);
                *(float4*)(C + (size_t)gm * N + gn) = v;
            }
        }
    }
}

// ---------------- KV: kv(b,c,z,t) = sum_h tanh(H[b,t,z*64+h]) * wql[c,z*64+h] ----
// grid (z=16, b=32), 256 threads; thread owns t=tid and t=tid+256 rows in VGPRs,
// wql rows are wave-uniform -> scalar loads.
__global__ __launch_bounds__(256) void kv_kernel(
    const float* __restrict__ H, const float* __restrict__ wql, float* __restrict__ kv)
{
    const int z = blockIdx.x;
    const int b = blockIdx.y;
    const int tid = threadIdx.x;
    float4 th0[16], th1[16];
    const float4* h0 = (const float4*)(H + ((size_t)b * T_LEN + tid) * D_MODEL + z * D_K);
    const float4* h1 = (const float4*)(H + ((size_t)b * T_LEN + tid + 256) * D_MODEL + z * D_K);
#pragma unroll
    for (int i = 0; i < 16; i++) { th0[i] = tanh4(h0[i]); th1[i] = tanh4(h1[i]); }
    for (int c = 0; c < N_CLASSES; c++) {
        const float4* w = (const float4*)(wql + (size_t)c * D_MODEL + z * D_K);
        float s0 = 0.f, s1 = 0.f;
#pragma unroll
        for (int i = 0; i < 16; i++) {
            const float4 wv = w[i];
            s0 += dot4(th0[i], wv);
            s1 += dot4(th1[i], wv);
        }
        const size_t base = (((size_t)b * N_CLASSES + c) * N_HEADS + z) * T_LEN;
        kv[base + tid] = s0;
        kv[base + tid + 256] = s1;
    }
}

// ---------------- Attention: per (b,c,z) block ----------------
// scores(s,t) = sum_h qproj[c,s,z*64+h] * wkt[b,t,z*64+h]; softmax over t per s;
// out(b,c) += (1/16) sum_s (sum_t e*kv) / (sum_t e)
__global__ __launch_bounds__(256) void attn_kernel(
    const float* __restrict__ qproj, const float* __restrict__ wkt,
    const float* __restrict__ kv, float* __restrict__ out)
{
    const int bx = blockIdx.x;
    const int c = bx & 31;          // fastest: consecutive blocks share (b,z) wkt slice in L2
    const int z = (bx >> 5) & 15;
    const int b = bx >> 9;
    const int tid = threadIdx.x;

    __shared__ float sc[16][513];
    __shared__ float kvs[512];
    __shared__ float wred[4];

    const size_t kvbase = (((size_t)b * N_CLASSES + c) * N_HEADS + z) * T_LEN;
    kvs[tid] = kv[kvbase + tid];
    kvs[tid + 256] = kv[kvbase + tid + 256];

    const float4* w0 = (const float4*)(wkt + ((size_t)b * T_LEN + tid) * D_MODEL + z * D_K);
    const float4* w1 = (const float4*)(wkt + ((size_t)b * T_LEN + tid + 256) * D_MODEL + z * D_K);
    const float* qb = qproj + ((size_t)c * S_LEN) * D_MODEL + z * D_K;

    float acc0[16], acc1[16];
#pragma unroll
    for (int s = 0; s < 16; s++) { acc0[s] = 0.f; acc1[s] = 0.f; }

#pragma unroll
    for (int h = 0; h < 16; h++) {
        const float4 a = w0[h];
        const float4 bb = w1[h];
#pragma unroll
        for (int s = 0; s < 16; s++) {
            const float4 q = *(const float4*)(qb + s * D_MODEL + h * 4);  // uniform -> s_load
            acc0[s] += q.x * a.x + q.y * a.y + q.z * a.z + q.w * a.w;
            acc1[s] += q.x * bb.x + q.y * bb.y + q.z * bb.z + q.w * bb.w;
        }
    }

#pragma unroll
    for (int s = 0; s < 16; s++) { sc[s][tid] = acc0[s]; sc[s][tid + 256] = acc1[s]; }
    __syncthreads();

    const int wave = tid >> 6;
    const int lane = tid & 63;
    float res = 0.f;
#pragma unroll
    for (int si = 0; si < 4; si++) {
        const int s = wave * 4 + si;
        float m = -1e30f;
#pragma unroll
        for (int j = 0; j < 8; j++) m = fmaxf(m, sc[s][lane + 64 * j]);
#pragma unroll
        for (int off = 32; off > 0; off >>= 1) m = fmaxf(m, __shfl_xor(m, off, 64));
        float den = 0.f, num = 0.f;
#pragma unroll
        for (int j = 0; j < 8; j++) {
            const float e = __expf(sc[s][lane + 64 * j] - m);
            den += e;
            num += e * kvs[lane + 64 * j];
        }
#pragma unroll
        for (int off = 32; off > 0; off >>= 1) {
            den += __shfl_xor(den, off, 64);
            num += __shfl_xor(num, off, 64);
        }
        res += num / den;
    }
    if (lane == 0) wred[wave] = res;
    __syncthreads();
    if (tid == 0) {
        const float tot = (wred[0] + wred[1] + wred[2] + wred[3]) * (1.0f / 16.0f);
        atomicAdd(out + (b * N_CLASSES + c), tot);
    }
}

extern "C" void kernel_launch(void* const* d_in, const int* in_sizes, int n_in,
                              void* d_out, int out_size, void* d_ws, size_t ws_size,
                              hipStream_t stream)
{
    const float* Q  = (const float*)d_in[0];   // (32,16,1024)
    const float* H  = (const float*)d_in[1];   // (32,512,1024)
    const float* ql = (const float*)d_in[2];   // (32,1024)
    const float* WQ = (const float*)d_in[3];   // (1024,1024)
    const float* WK = (const float*)d_in[4];
    const float* WV = (const float*)d_in[5];
    float* out = (float*)d_out;                // (32,32)

    char* ws = (char*)d_ws;
    float* qproj = (float*)(ws);                                    // 512*1024 f32   (2 MB)
    float* wqlb  = (float*)(ws + (size_t)(2 << 20));                // 32*1024 f32
    float* wkt   = (float*)(ws + (size_t)(4 << 20));                // 16384*1024 f32 (64 MB)
    float* kv    = (float*)(ws + (size_t)(4 << 20) + ((size_t)64 << 20)); // 32*32*16*512 f32 (33.5 MB)

    hipMemsetAsync(d_out, 0, (size_t)out_size * sizeof(float), stream);

    dim3 thr(256);
    // q_s = Q @ WQ^T              (512 x 1024)
    sgemm_bt<<<dim3(8, 4), thr, 0, stream>>>(Q, WQ, qproj, 512, 1024, 1024, 0);
    // WK_t = tanh(H @ WK^T)       (16384 x 1024)  -- dominant GEMM
    sgemm_bt<<<dim3(8, 128), thr, 0, stream>>>(H, WK, wkt, 16384, 1024, 1024, 1);
    // Wql = ql @ WV^T             (32 x 1024)
    sgemm_bt<<<dim3(8, 1), thr, 0, stream>>>(ql, WV, wqlb, 32, 1024, 1024, 0);
    // KV(b,c,z,t)
    kv_kernel<<<dim3(16, 32), thr, 0, stream>>>(H, wqlb, kv);
    // scores + softmax + mean_s + dot with KV, atomic over z
    attn_kernel<<<dim3(16384), thr, 0, stream>>>(qproj, wkt, kv, out);
}

// Round 2
// 481.177 us; speedup vs baseline: 2.9440x; 2.9440x over previous
//
#include <hip/hip_runtime.h>
#include <hip/hip_bf16.h>
#include <math.h>

#define D_MODEL 1024
#define N_HEADS 16
#define D_K 64
#define N_CLASSES 32
#define S_LEN 16
#define BATCH 32
#define T_LEN 512

typedef __bf16 bf16_t;
typedef bf16_t bf16x8 __attribute__((ext_vector_type(8)));
typedef float f32x4 __attribute__((ext_vector_type(4)));

__device__ inline unsigned short f2bf(float f) {
    unsigned int u = __float_as_uint(f);
    unsigned int r = (u + 0x7FFFu + ((u >> 16) & 1u)) >> 16;   // RNE
    return (unsigned short)r;
}
__device__ inline float4 tanh4(float4 v) {
    return make_float4(tanhf(v.x), tanhf(v.y), tanhf(v.z), tanhf(v.w));
}
__device__ inline float dot4(float4 a, float4 b) {
    return a.x * b.x + a.y * b.y + a.z * b.z + a.w * b.w;
}

// async global->LDS, 16 bytes per lane (global_load_lds_dwordx4)
__device__ inline void async16(void* lds, const void* g) {
    __builtin_amdgcn_global_load_lds(
        (const __attribute__((address_space(1))) unsigned int*)g,
        (__attribute__((address_space(3))) unsigned int*)lds, 16, 0, 0);
}

// ---------------- fp32 -> bf16 conversion ----------------
__global__ __launch_bounds__(256) void cvt_bf16(
    const float4* __restrict__ in, ushort4* __restrict__ out, int n4)
{
    int i = blockIdx.x * 256 + threadIdx.x;
    if (i < n4) {
        float4 v = in[i];
        ushort4 o;
        o.x = f2bf(v.x); o.y = f2bf(v.y); o.z = f2bf(v.z); o.w = f2bf(v.w);
        out[i] = o;
    }
}

// ---------------- bf16 MFMA GEMM: C = op(A @ B^T), bf16 out ----------------
// A: (M,K) bf16 row-major, B: (N,K) bf16 row-major, C: (M,N) bf16 row-major.
// M,N multiples of 128. 128x128 tile, BK=32, 256 thr = 4 waves (2x2 of 64x64),
// 4x4 acc tiles of 16x16x32 per wave. m97-ladder structure.
__global__ __launch_bounds__(256) void gemm_bf16_bt(
    const unsigned short* __restrict__ A, const unsigned short* __restrict__ B,
    unsigned short* __restrict__ C, int M, int N, int K, int applyTanh)
{
    __shared__ unsigned short As[128 * 32];   // 8 KB
    __shared__ unsigned short Bs[128 * 32];   // 8 KB
    const int tid = threadIdx.x;
    const int m0 = blockIdx.y * 128;
    const int n0 = blockIdx.x * 128;
    const int wid = tid >> 6;
    const int lane = tid & 63;
    const int quad = lane >> 4;
    const int l16 = lane & 15;
    const int wm = (wid >> 1) * 64;
    const int wn = (wid & 1) * 64;

    f32x4 acc[4][4] = {};

    const int r0 = tid >> 2;          // staging row 0..63
    const int cc0 = (tid & 3) * 8;    // k-offset within 32 (elements)

    for (int k0 = 0; k0 < K; k0 += 32) {
        async16(&As[tid * 8],        A + (size_t)(m0 + r0) * K + k0 + cc0);
        async16(&As[2048 + tid * 8], A + (size_t)(m0 + 64 + r0) * K + k0 + cc0);
        async16(&Bs[tid * 8],        B + (size_t)(n0 + r0) * K + k0 + cc0);
        async16(&Bs[2048 + tid * 8], B + (size_t)(n0 + 64 + r0) * K + k0 + cc0);
        __syncthreads();

        bf16x8 af[4], bfr[4];
#pragma unroll
        for (int mt = 0; mt < 4; mt++)
            af[mt] = *(const bf16x8*)&As[(wm + mt * 16 + l16) * 32 + quad * 8];
#pragma unroll
        for (int nt = 0; nt < 4; nt++)
            bfr[nt] = *(const bf16x8*)&Bs[(wn + nt * 16 + l16) * 32 + quad * 8];
#pragma unroll
        for (int mt = 0; mt < 4; mt++)
#pragma unroll
            for (int nt = 0; nt < 4; nt++)
                acc[mt][nt] = __builtin_amdgcn_mfma_f32_16x16x32_bf16(
                    af[mt], bfr[nt], acc[mt][nt], 0, 0, 0);
        __syncthreads();
    }

#pragma unroll
    for (int mt = 0; mt < 4; mt++)
#pragma unroll
        for (int nt = 0; nt < 4; nt++)
#pragma unroll
            for (int r = 0; r < 4; r++) {
                const int row = m0 + wm + mt * 16 + quad * 4 + r;
                const int col = n0 + wn + nt * 16 + l16;
                float v = acc[mt][nt][r];
                if (applyTanh) v = tanhf(v);
                C[(size_t)row * N + col] = f2bf(v);
            }
}

// ---------------- fp32 SGEMM (small): C = A @ B^T, fp32 out ----------------
__global__ __launch_bounds__(256) void sgemm_bt(
    const float* __restrict__ A, const float* __restrict__ B,
    float* __restrict__ C, int M, int N, int K)
{
    __shared__ float Asb[16][132];
    __shared__ float Bsb[16][132];
    const int tid = threadIdx.x;
    const int n0 = blockIdx.x * 128;
    const int m0 = blockIdx.y * 128;
    const int tx = tid & 15;
    const int ty = tid >> 4;
    const int lr = tid >> 2;
    const int lk = (tid & 3) << 2;

    float acc[8][8];
#pragma unroll
    for (int i = 0; i < 8; i++)
#pragma unroll
        for (int j = 0; j < 8; j++) acc[i][j] = 0.f;

    for (int k0 = 0; k0 < K; k0 += 16) {
#pragma unroll
        for (int h = 0; h < 2; h++) {
            const int row = lr + h * 64;
            const int gm = m0 + row;
            float4 v = make_float4(0.f, 0.f, 0.f, 0.f);
            if (gm < M) v = *(const float4*)(A + (size_t)gm * K + k0 + lk);
            Asb[lk + 0][row] = v.x; Asb[lk + 1][row] = v.y;
            Asb[lk + 2][row] = v.z; Asb[lk + 3][row] = v.w;
        }
#pragma unroll
        for (int h = 0; h < 2; h++) {
            const int row = lr + h * 64;
            float4 v = *(const float4*)(B + (size_t)(n0 + row) * K + k0 + lk);
            Bsb[lk + 0][row] = v.x; Bsb[lk + 1][row] = v.y;
            Bsb[lk + 2][row] = v.z; Bsb[lk + 3][row] = v.w;
        }
        __syncthreads();
#pragma unroll
        for (int k = 0; k < 16; k++) {
            const float4 a0 = *(const float4*)(&Asb[k][4 * ty]);
            const float4 a1 = *(const float4*)(&Asb[k][4 * ty + 64]);
            const float4 b0 = *(const float4*)(&Bsb[k][4 * tx]);
            const float4 b1 = *(const float4*)(&Bsb[k][4 * tx + 64]);
            const float ar[8] = {a0.x, a0.y, a0.z, a0.w, a1.x, a1.y, a1.z, a1.w};
            const float br[8] = {b0.x, b0.y, b0.z, b0.w, b1.x, b1.y, b1.z, b1.w};
#pragma unroll
            for (int i = 0; i < 8; i++)
#pragma unroll
                for (int j = 0; j < 8; j++) acc[i][j] += ar[i] * br[j];
        }
        __syncthreads();
    }
#pragma unroll
    for (int i = 0; i < 8; i++) {
        const int gm = m0 + ((i < 4) ? (4 * ty + i) : (64 + 4 * ty + (i - 4)));
        if (gm < M) {
#pragma unroll
            for (int jh = 0; jh < 2; jh++) {
                const int gn = n0 + 4 * tx + jh * 64;
                *(float4*)(C + (size_t)gm * N + gn) =
                    make_float4(acc[i][jh * 4 + 0], acc[i][jh * 4 + 1],
                                acc[i][jh * 4 + 2], acc[i][jh * 4 + 3]);
            }
        }
    }
}

// ---------------- KV: kv(b,c,z,t) = sum_h tanh(H[b,t,z*64+h]) * wql[c,z*64+h]
__global__ __launch_bounds__(256) void kv_kernel(
    const float* __restrict__ H, const float* __restrict__ wql, float* __restrict__ kv)
{
    const int z = blockIdx.x;
    const int b = blockIdx.y;
    const int tid = threadIdx.x;
    float4 th0[16], th1[16];
    const float4* h0 = (const float4*)(H + ((size_t)b * T_LEN + tid) * D_MODEL + z * D_K);
    const float4* h1 = (const float4*)(H + ((size_t)b * T_LEN + tid + 256) * D_MODEL + z * D_K);
#pragma unroll
    for (int i = 0; i < 16; i++) { th0[i] = tanh4(h0[i]); th1[i] = tanh4(h1[i]); }
    for (int c = 0; c < N_CLASSES; c++) {
        const float4* w = (const float4*)(wql + (size_t)c * D_MODEL + z * D_K);
        float s0 = 0.f, s1 = 0.f;
#pragma unroll
        for (int i = 0; i < 16; i++) {
            const float4 wv = w[i];
            s0 += dot4(th0[i], wv);
            s1 += dot4(th1[i], wv);
        }
        const size_t base = (((size_t)b * N_CLASSES + c) * N_HEADS + z) * T_LEN;
        kv[base + tid] = s0;
        kv[base + tid + 256] = s1;
    }
}

// ---------------- Attention via MFMA: block per (b,z), 4 waves x 8 c-tiles ---
// scores row = c*16+s, col = t.  No max-subtraction needed (|score| <= 64).
__global__ __launch_bounds__(256) void attn_mfma(
    const unsigned short* __restrict__ qproj, const unsigned short* __restrict__ wkt,
    const float* __restrict__ kv, float* __restrict__ out)
{
    __shared__ float kvs[32 * 512];   // 64 KB, [c][t]
    const int z = blockIdx.x;
    const int b = blockIdx.y;
    const int tid = threadIdx.x;
    const int wid = tid >> 6;
    const int lane = tid & 63;
    const int quad = lane >> 4;
    const int l16 = lane & 15;

    // stage kv[b,:,z,:] -> kvs[c][t]
    for (int i = tid; i < 4096; i += 256) {
        const int c = i >> 7, rem = i & 127;
        ((float4*)kvs)[i] =
            ((const float4*)kv)[(((size_t)b * N_CLASSES + c) * N_HEADS + z) * 128 + rem];
    }

    // resident A-frags: qproj rows (c*16 + l16), k = kh*32 + quad*8
    bf16x8 af[8][2];
#pragma unroll
    for (int ct = 0; ct < 8; ct++)
#pragma unroll
        for (int kh = 0; kh < 2; kh++)
            af[ct][kh] = *(const bf16x8*)(qproj +
                (size_t)((wid * 8 + ct) * 16 + l16) * D_MODEL + z * D_K + kh * 32 + quad * 8);
    __syncthreads();

    float den[8][4], num[8][4];
#pragma unroll
    for (int ct = 0; ct < 8; ct++)
#pragma unroll
        for (int r = 0; r < 4; r++) { den[ct][r] = 0.f; num[ct][r] = 0.f; }

    const unsigned short* wb = wkt + (size_t)(b * T_LEN) * D_MODEL + z * D_K;
    for (int nt = 0; nt < 32; nt++) {
        const bf16x8 b0 = *(const bf16x8*)(wb + (size_t)(nt * 16 + l16) * D_MODEL + quad * 8);
        const bf16x8 b1 = *(const bf16x8*)(wb + (size_t)(nt * 16 + l16) * D_MODEL + 32 + quad * 8);
#pragma unroll
        for (int ct = 0; ct < 8; ct++) {
            f32x4 a = {};
            a = __builtin_amdgcn_mfma_f32_16x16x32_bf16(af[ct][0], b0, a, 0, 0, 0);
            a = __builtin_amdgcn_mfma_f32_16x16x32_bf16(af[ct][1], b1, a, 0, 0, 0);
            const float kvv = kvs[(wid * 8 + ct) * 512 + nt * 16 + l16];
#pragma unroll
            for (int r = 0; r < 4; r++) {
                const float e = __expf(a[r]);
                den[ct][r] += e;
                num[ct][r] += e * kvv;
            }
        }
    }

    // reduce across the 16 lanes of each quad (cols), then combine rows/quads
#pragma unroll
    for (int ct = 0; ct < 8; ct++) {
        float s = 0.f;
#pragma unroll
        for (int r = 0; r < 4; r++) {
            float d = den[ct][r], n = num[ct][r];
#pragma unroll
            for (int off = 1; off < 16; off <<= 1) {
                d += __shfl_xor(d, off, 64);
                n += __shfl_xor(n, off, 64);
            }
            s += n / d;            // per-row num/den; rows of this quad
        }
        s += __shfl_xor(s, 16, 64);
        s += __shfl_xor(s, 32, 64);
        if (lane == 0)
            atomicAdd(&out[b * N_CLASSES + wid * 8 + ct], s * (1.0f / 16.0f));
    }
}

extern "C" void kernel_launch(void* const* d_in, const int* in_sizes, int n_in,
                              void* d_out, int out_size, void* d_ws, size_t ws_size,
                              hipStream_t stream)
{
    const float* Q  = (const float*)d_in[0];   // (32,16,1024)
    const float* H  = (const float*)d_in[1];   // (32,512,1024)
    const float* ql = (const float*)d_in[2];   // (32,1024)
    const float* WQ = (const float*)d_in[3];   // (1024,1024)
    const float* WK = (const float*)d_in[4];
    const float* WV = (const float*)d_in[5];
    float* out = (float*)d_out;                // (32,32)

    char* ws = (char*)d_ws;
    // region A (0..33.5MB): Hb first; after wkt GEMM it is dead and overlaid
    unsigned short* Hb    = (unsigned short*)(ws);                       // 33.5 MB
    unsigned short* wkt_b = (unsigned short*)(ws + (size_t)33554432);    // 33.5 MB
    float*          kv    = (float*)(ws + (size_t)67108864);             // 33.5 MB
    unsigned short* WKb   = (unsigned short*)(ws + (size_t)100663296);   // 2 MB
    // overlays into region A (used only after wkt GEMM):
    unsigned short* Qb      = (unsigned short*)(ws);                     // 1 MB
    unsigned short* WQb     = (unsigned short*)(ws + (size_t)(1 << 20)); // 2 MB
    unsigned short* qproj_b = (unsigned short*)(ws + (size_t)(3 << 20)); // 1 MB
    float*          wqlb    = (float*)(ws + (size_t)(4 << 20));          // 128 KB

    hipMemsetAsync(d_out, 0, (size_t)out_size * sizeof(float), stream);

    dim3 thr(256);
    // bf16 conversions for the dominant GEMM
    cvt_bf16<<<dim3(16384), thr, 0, stream>>>((const float4*)H, (ushort4*)Hb, 4194304);
    cvt_bf16<<<dim3(1024), thr, 0, stream>>>((const float4*)WK, (ushort4*)WKb, 262144);
    // wkt = tanh(H @ WK^T)  (16384 x 1024), bf16 out
    gemm_bf16_bt<<<dim3(8, 128), thr, 0, stream>>>(Hb, WKb, wkt_b, 16384, 1024, 1024, 1);
    // Hb dead -> overlay region A
    cvt_bf16<<<dim3(512), thr, 0, stream>>>((const float4*)Q, (ushort4*)Qb, 131072);
    cvt_bf16<<<dim3(1024), thr, 0, stream>>>((const float4*)WQ, (ushort4*)WQb, 262144);
    // qproj = Q @ WQ^T  (512 x 1024), bf16 out
    gemm_bf16_bt<<<dim3(8, 4), thr, 0, stream>>>(Qb, WQb, qproj_b, 512, 1024, 1024, 0);
    // Wql = ql @ WV^T  (32 x 1024), fp32 (feeds kv; keep full precision)
    sgemm_bt<<<dim3(8, 1), thr, 0, stream>>>(ql, WV, wqlb, 32, 1024, 1024);
    // kv(b,c,z,t), fp32
    kv_kernel<<<dim3(16, 32), thr, 0, stream>>>(H, wqlb, kv);
    // fused scores -> softmax -> dot(kv) -> mean_s, atomic over z
    attn_mfma<<<dim3(16, 32), thr, 0, stream>>>(qproj_b, wkt_b, kv, out);
}

// Round 4
// 347.714 us; speedup vs baseline: 4.0740x; 1.3838x over previous
//
#include <hip/hip_runtime.h>
#include <hip/hip_bf16.h>
#include <math.h>

#define D_MODEL 1024
#define N_HEADS 16
#define D_K 64
#define N_CLASSES 32
#define S_LEN 16
#define BATCH 32
#define T_LEN 512

typedef __bf16 bf16_t;
typedef bf16_t bf16x8 __attribute__((ext_vector_type(8)));
typedef float f32x4 __attribute__((ext_vector_type(4)));

__device__ inline unsigned short f2bf(float f) {
    unsigned int u = __float_as_uint(f);
    unsigned int r = (u + 0x7FFFu + ((u >> 16) & 1u)) >> 16;   // RNE
    return (unsigned short)r;
}
__device__ inline float4 tanh4(float4 v) {
    return make_float4(tanhf(v.x), tanhf(v.y), tanhf(v.z), tanhf(v.w));
}
__device__ inline float dot4(float4 a, float4 b) {
    return a.x * b.x + a.y * b.y + a.z * b.z + a.w * b.w;
}

// async global->LDS, 16 bytes per lane (global_load_lds_dwordx4)
__device__ inline void async16(void* lds, const void* g) {
    __builtin_amdgcn_global_load_lds(
        (const __attribute__((address_space(1))) unsigned int*)g,
        (__attribute__((address_space(3))) unsigned int*)lds, 16, 0, 0);
}

// ---------------- fp32 -> bf16 conversion ----------------
__global__ __launch_bounds__(256) void cvt_bf16(
    const float4* __restrict__ in, ushort4* __restrict__ out, int n4)
{
    int i = blockIdx.x * 256 + threadIdx.x;
    if (i < n4) {
        float4 v = in[i];
        ushort4 o;
        o.x = f2bf(v.x); o.y = f2bf(v.y); o.z = f2bf(v.z); o.w = f2bf(v.w);
        out[i] = o;
    }
}

// ---------------- bf16 MFMA GEMM: C = op(A @ B^T), bf16 out ----------------
// A: (M,K) bf16 row-major, B: (N,K) bf16 row-major, C: (M,N) bf16 row-major.
// M,N multiples of 128. 128x128 tile, BK=32, 256 thr = 4 waves (2x2 of 64x64),
// 4x4 acc tiles of 16x16x32 per wave. m97-ladder structure.
__global__ __launch_bounds__(256) void gemm_bf16_bt(
    const unsigned short* __restrict__ A, const unsigned short* __restrict__ B,
    unsigned short* __restrict__ C, int M, int N, int K, int applyTanh)
{
    __shared__ unsigned short As[128 * 32];   // 8 KB
    __shared__ unsigned short Bs[128 * 32];   // 8 KB
    const int tid = threadIdx.x;
    const int m0 = blockIdx.y * 128;
    const int n0 = blockIdx.x * 128;
    const int wid = tid >> 6;
    const int lane = tid & 63;
    const int quad = lane >> 4;
    const int l16 = lane & 15;
    const int wm = (wid >> 1) * 64;
    const int wn = (wid & 1) * 64;

    f32x4 acc[4][4] = {};

    const int r0 = tid >> 2;          // staging row 0..63
    const int cc0 = (tid & 3) * 8;    // k-offset within 32 (elements)

    for (int k0 = 0; k0 < K; k0 += 32) {
        async16(&As[tid * 8],        A + (size_t)(m0 + r0) * K + k0 + cc0);
        async16(&As[2048 + tid * 8], A + (size_t)(m0 + 64 + r0) * K + k0 + cc0);
        async16(&Bs[tid * 8],        B + (size_t)(n0 + r0) * K + k0 + cc0);
        async16(&Bs[2048 + tid * 8], B + (size_t)(n0 + 64 + r0) * K + k0 + cc0);
        __syncthreads();

        bf16x8 af[4], bfr[4];
#pragma unroll
        for (int mt = 0; mt < 4; mt++)
            af[mt] = *(const bf16x8*)&As[(wm + mt * 16 + l16) * 32 + quad * 8];
#pragma unroll
        for (int nt = 0; nt < 4; nt++)
            bfr[nt] = *(const bf16x8*)&Bs[(wn + nt * 16 + l16) * 32 + quad * 8];
#pragma unroll
        for (int mt = 0; mt < 4; mt++)
#pragma unroll
            for (int nt = 0; nt < 4; nt++)
                acc[mt][nt] = __builtin_amdgcn_mfma_f32_16x16x32_bf16(
                    af[mt], bfr[nt], acc[mt][nt], 0, 0, 0);
        __syncthreads();
    }

#pragma unroll
    for (int mt = 0; mt < 4; mt++)
#pragma unroll
        for (int nt = 0; nt < 4; nt++)
#pragma unroll
            for (int r = 0; r < 4; r++) {
                const int row = m0 + wm + mt * 16 + quad * 4 + r;
                const int col = n0 + wn + nt * 16 + l16;
                float v = acc[mt][nt][r];
                if (applyTanh) v = tanhf(v);
                C[(size_t)row * N + col] = f2bf(v);
            }
}

// ---------------- wql = ql @ WV^T (32 x 1024, K=1024), fp32, split-K -------
// grid (16, 8): n0 = bx*64, k0 = by*128. 256 threads. atomicAdd partials.
// NOTE: wqlb must be zeroed AFTER the H->Hb conversion (overlay ordering).
__global__ __launch_bounds__(256) void wql_kernel(
    const float* __restrict__ ql, const float* __restrict__ WV, float* __restrict__ wql)
{
    __shared__ float4 qls[32][32];      // [c][kq]   16 KB
    __shared__ float4 WVs[64][33];      // [n][kq]+pad 33.8 KB
    const int tid = threadIdx.x;
    const int n0 = blockIdx.x * 64;
    const int k0 = blockIdx.y * 128;

    for (int i = tid; i < 1024; i += 256)
        qls[i >> 5][i & 31] = *(const float4*)(ql + (size_t)(i >> 5) * D_MODEL + k0 + (i & 31) * 4);
    for (int i = tid; i < 2048; i += 256)
        WVs[i >> 5][i & 31] = *(const float4*)(WV + (size_t)(n0 + (i >> 5)) * D_MODEL + k0 + (i & 31) * 4);
    __syncthreads();

    const int n = tid & 63;
    const int c0 = (tid >> 6) * 8;
    float acc[8] = {};
    for (int kq = 0; kq < 32; kq++) {
        const float4 wv = WVs[n][kq];
#pragma unroll
        for (int c = 0; c < 8; c++) acc[c] += dot4(qls[c0 + c][kq], wv);
    }
#pragma unroll
    for (int c = 0; c < 8; c++)
        atomicAdd(&wql[(size_t)(c0 + c) * D_MODEL + n0 + n], acc[c]);
}

// ---------------- KV: kv(b,c,z,t) = sum_h tanh(H[b,t,z*64+h]) * wql[c,z*64+h]
__global__ __launch_bounds__(256) void kv_kernel(
    const float* __restrict__ H, const float* __restrict__ wql, float* __restrict__ kv)
{
    const int z = blockIdx.x;
    const int b = blockIdx.y;
    const int tid = threadIdx.x;
    float4 th0[16], th1[16];
    const float4* h0 = (const float4*)(H + ((size_t)b * T_LEN + tid) * D_MODEL + z * D_K);
    const float4* h1 = (const float4*)(H + ((size_t)b * T_LEN + tid + 256) * D_MODEL + z * D_K);
#pragma unroll
    for (int i = 0; i < 16; i++) { th0[i] = tanh4(h0[i]); th1[i] = tanh4(h1[i]); }
    for (int c = 0; c < N_CLASSES; c++) {
        const float4* w = (const float4*)(wql + (size_t)c * D_MODEL + z * D_K);
        float s0 = 0.f, s1 = 0.f;
#pragma unroll
        for (int i = 0; i < 16; i++) {
            const float4 wv = w[i];
            s0 += dot4(th0[i], wv);
            s1 += dot4(th1[i], wv);
        }
        const size_t base = (((size_t)b * N_CLASSES + c) * N_HEADS + z) * T_LEN;
        kv[base + tid] = s0;
        kv[base + tid + 256] = s1;
    }
}

// ---------------- Attention via MFMA: block per (b,z), 4 waves x 8 c-tiles ---
// wkt (b,z)-slice staged to LDS via global_load_lds; kv read direct from L2.
// No max-subtraction needed: |score| <= 64 so exp() can't overflow fp32.
__global__ __launch_bounds__(256) void attn_mfma(
    const unsigned short* __restrict__ qproj, const unsigned short* __restrict__ wkt,
    const float* __restrict__ kv, float* __restrict__ out)
{
    __shared__ unsigned short wkts[512 * 64];   // 64 KB, [t][k]
    const int z = blockIdx.x;
    const int b = blockIdx.y;
    const int tid = threadIdx.x;
    const int wid = tid >> 6;
    const int lane = tid & 63;
    const int quad = lane >> 4;
    const int l16 = lane & 15;

    const unsigned short* wb = wkt + (size_t)(b * T_LEN) * D_MODEL + z * D_K;
    // stage 512 rows x 128 B = 64 KB as 4096 16B chunks (coalesced 128B/8 lanes)
#pragma unroll
    for (int it = 0; it < 16; it++) {
        const int chunk = it * 256 + tid;
        async16(&wkts[chunk * 8], wb + (size_t)(chunk >> 3) * D_MODEL + (chunk & 7) * 8);
    }

    // resident A-frags while staging is in flight
    bf16x8 af[8][2];
#pragma unroll
    for (int ct = 0; ct < 8; ct++)
#pragma unroll
        for (int kh = 0; kh < 2; kh++)
            af[ct][kh] = *(const bf16x8*)(qproj +
                (size_t)((wid * 8 + ct) * 16 + l16) * D_MODEL + z * D_K + kh * 32 + quad * 8);
    __syncthreads();

    float den[8][4], num[8][4];
#pragma unroll
    for (int ct = 0; ct < 8; ct++)
#pragma unroll
        for (int r = 0; r < 4; r++) { den[ct][r] = 0.f; num[ct][r] = 0.f; }

    const float* kvb = kv + (((size_t)b * N_CLASSES) * N_HEADS + z) * T_LEN;
    for (int nt = 0; nt < 32; nt++) {
        const bf16x8 b0 = *(const bf16x8*)&wkts[(nt * 16 + l16) * 64 + quad * 8];
        const bf16x8 b1 = *(const bf16x8*)&wkts[(nt * 16 + l16) * 64 + 32 + quad * 8];
#pragma unroll
        for (int ct = 0; ct < 8; ct++) {
            f32x4 a = {};
            a = __builtin_amdgcn_mfma_f32_16x16x32_bf16(af[ct][0], b0, a, 0, 0, 0);
            a = __builtin_amdgcn_mfma_f32_16x16x32_bf16(af[ct][1], b1, a, 0, 0, 0);
            const float kvv = kvb[(size_t)(wid * 8 + ct) * (N_HEADS * T_LEN) + nt * 16 + l16];
#pragma unroll
            for (int r = 0; r < 4; r++) {
                const float e = __expf(a[r]);
                den[ct][r] += e;
                num[ct][r] += e * kvv;
            }
        }
    }

    // reduce across the 16 lanes of each quad (cols), then combine rows/quads
#pragma unroll
    for (int ct = 0; ct < 8; ct++) {
        float s = 0.f;
#pragma unroll
        for (int r = 0; r < 4; r++) {
            float d = den[ct][r], n = num[ct][r];
#pragma unroll
            for (int off = 1; off < 16; off <<= 1) {
                d += __shfl_xor(d, off, 64);
                n += __shfl_xor(n, off, 64);
            }
            s += n / d;            // per-row num/den
        }
        s += __shfl_xor(s, 16, 64);
        s += __shfl_xor(s, 32, 64);
        if (lane == 0)
            atomicAdd(&out[b * N_CLASSES + wid * 8 + ct], s * (1.0f / 16.0f));
    }
}

extern "C" void kernel_launch(void* const* d_in, const int* in_sizes, int n_in,
                              void* d_out, int out_size, void* d_ws, size_t ws_size,
                              hipStream_t stream)
{
    const float* Q  = (const float*)d_in[0];   // (32,16,1024)
    const float* H  = (const float*)d_in[1];   // (32,512,1024)
    const float* ql = (const float*)d_in[2];   // (32,1024)
    const float* WQ = (const float*)d_in[3];   // (1024,1024)
    const float* WK = (const float*)d_in[4];
    const float* WV = (const float*)d_in[5];
    float* out = (float*)d_out;                // (32,32)

    char* ws = (char*)d_ws;
    // region A (0..33.5MB): Hb first; after wkt GEMM it is dead and overlaid
    unsigned short* Hb    = (unsigned short*)(ws);                       // 33.5 MB
    unsigned short* wkt_b = (unsigned short*)(ws + (size_t)33554432);    // 33.5 MB
    float*          kv    = (float*)(ws + (size_t)67108864);             // 33.5 MB
    unsigned short* WKb   = (unsigned short*)(ws + (size_t)100663296);   // 2 MB
    // overlays into region A (used only after wkt GEMM / H conversion):
    unsigned short* Qb      = (unsigned short*)(ws);                     // 1 MB
    unsigned short* WQb     = (unsigned short*)(ws + (size_t)(1 << 20)); // 2 MB
    unsigned short* qproj_b = (unsigned short*)(ws + (size_t)(3 << 20)); // 1 MB
    float*          wqlb    = (float*)(ws + (size_t)(4 << 20));          // 128 KB

    hipMemsetAsync(d_out, 0, (size_t)out_size * sizeof(float), stream);

    dim3 thr(256);
    // bf16 conversions for the dominant GEMM
    cvt_bf16<<<dim3(16384), thr, 0, stream>>>((const float4*)H, (ushort4*)Hb, 4194304);
    cvt_bf16<<<dim3(1024), thr, 0, stream>>>((const float4*)WK, (ushort4*)WKb, 262144);
    // wkt = tanh(H @ WK^T)  (16384 x 1024), bf16 out
    gemm_bf16_bt<<<dim3(8, 128), thr, 0, stream>>>(Hb, WKb, wkt_b, 16384, 1024, 1024, 1);
    // Hb dead -> overlay region A
    cvt_bf16<<<dim3(512), thr, 0, stream>>>((const float4*)Q, (ushort4*)Qb, 131072);
    cvt_bf16<<<dim3(1024), thr, 0, stream>>>((const float4*)WQ, (ushort4*)WQb, 262144);
    // qproj = Q @ WQ^T  (512 x 1024), bf16 out
    gemm_bf16_bt<<<dim3(8, 4), thr, 0, stream>>>(Qb, WQb, qproj_b, 512, 1024, 1024, 0);
    // zero wqlb ONLY NOW (cvt_bf16(H->Hb) above writes through this region;
    // round-3 bug was issuing this memset before the conversion)
    hipMemsetAsync(wqlb, 0, (size_t)N_CLASSES * D_MODEL * sizeof(float), stream);
    // Wql = ql @ WV^T  (32 x 1024), fp32 split-K
    wql_kernel<<<dim3(16, 8), thr, 0, stream>>>(ql, WV, wqlb);
    // kv(b,c,z,t), fp32
    kv_kernel<<<dim3(16, 32), thr, 0, stream>>>(H, wqlb, kv);
    // fused scores -> softmax -> dot(kv) -> mean_s, atomic over z
    attn_mfma<<<dim3(16, 32), thr, 0, stream>>>(qproj_b, wkt_b, kv, out);
}

// Round 5
// 294.809 us; speedup vs baseline: 4.8051x; 1.1795x over previous
//
#include <hip/hip_runtime.h>
#include <hip/hip_bf16.h>
#include <math.h>

#define D_MODEL 1024
#define N_HEADS 16
#define D_K 64
#define N_CLASSES 32
#define S_LEN 16
#define BATCH 32
#define T_LEN 512

typedef __bf16 bf16_t;
typedef bf16_t bf16x8 __attribute__((ext_vector_type(8)));
typedef float f32x4 __attribute__((ext_vector_type(4)));

__device__ inline unsigned short f2bf(float f) {
    unsigned int u = __float_as_uint(f);
    unsigned int r = (u + 0x7FFFu + ((u >> 16) & 1u)) >> 16;   // RNE
    return (unsigned short)r;
}
__device__ inline float4 tanh4(float4 v) {
    return make_float4(tanhf(v.x), tanhf(v.y), tanhf(v.z), tanhf(v.w));
}
__device__ inline float dot4(float4 a, float4 b) {
    return a.x * b.x + a.y * b.y + a.z * b.z + a.w * b.w;
}

// async global->LDS, 16 bytes per lane (global_load_lds_dwordx4)
__device__ inline void async16(void* lds, const void* g) {
    __builtin_amdgcn_global_load_lds(
        (const __attribute__((address_space(1))) unsigned int*)g,
        (__attribute__((address_space(3))) unsigned int*)lds, 16, 0, 0);
}

// ---------------- fp32 -> bf16 conversion ----------------
__global__ __launch_bounds__(256) void cvt_bf16(
    const float4* __restrict__ in, ushort4* __restrict__ out, int n4)
{
    int i = blockIdx.x * 256 + threadIdx.x;
    if (i < n4) {
        float4 v = in[i];
        ushort4 o;
        o.x = f2bf(v.x); o.y = f2bf(v.y); o.z = f2bf(v.z); o.w = f2bf(v.w);
        out[i] = o;
    }
}

// ---------------- bf16 MFMA GEMM: C = op(A @ B^T), bf16 out ----------------
// A: (M,K) bf16 row-major, B: (N,K) bf16 row-major, C: (M,N) bf16 row-major.
// M,N multiples of 128. 128x128 tile, BK=32, 256 thr = 4 waves (2x2 of 64x64),
// 4x4 acc tiles of 16x16x32 per wave. m97-ladder structure.
__global__ __launch_bounds__(256) void gemm_bf16_bt(
    const unsigned short* __restrict__ A, const unsigned short* __restrict__ B,
    unsigned short* __restrict__ C, int M, int N, int K, int applyTanh)
{
    __shared__ unsigned short As[128 * 32];   // 8 KB
    __shared__ unsigned short Bs[128 * 32];   // 8 KB
    const int tid = threadIdx.x;
    const int m0 = blockIdx.y * 128;
    const int n0 = blockIdx.x * 128;
    const int wid = tid >> 6;
    const int lane = tid & 63;
    const int quad = lane >> 4;
    const int l16 = lane & 15;
    const int wm = (wid >> 1) * 64;
    const int wn = (wid & 1) * 64;

    f32x4 acc[4][4] = {};

    const int r0 = tid >> 2;          // staging row 0..63
    const int cc0 = (tid & 3) * 8;    // k-offset within 32 (elements)

    for (int k0 = 0; k0 < K; k0 += 32) {
        async16(&As[tid * 8],        A + (size_t)(m0 + r0) * K + k0 + cc0);
        async16(&As[2048 + tid * 8], A + (size_t)(m0 + 64 + r0) * K + k0 + cc0);
        async16(&Bs[tid * 8],        B + (size_t)(n0 + r0) * K + k0 + cc0);
        async16(&Bs[2048 + tid * 8], B + (size_t)(n0 + 64 + r0) * K + k0 + cc0);
        __syncthreads();

        bf16x8 af[4], bfr[4];
#pragma unroll
        for (int mt = 0; mt < 4; mt++)
            af[mt] = *(const bf16x8*)&As[(wm + mt * 16 + l16) * 32 + quad * 8];
#pragma unroll
        for (int nt = 0; nt < 4; nt++)
            bfr[nt] = *(const bf16x8*)&Bs[(wn + nt * 16 + l16) * 32 + quad * 8];
#pragma unroll
        for (int mt = 0; mt < 4; mt++)
#pragma unroll
            for (int nt = 0; nt < 4; nt++)
                acc[mt][nt] = __builtin_amdgcn_mfma_f32_16x16x32_bf16(
                    af[mt], bfr[nt], acc[mt][nt], 0, 0, 0);
        __syncthreads();
    }

#pragma unroll
    for (int mt = 0; mt < 4; mt++)
#pragma unroll
        for (int nt = 0; nt < 4; nt++)
#pragma unroll
            for (int r = 0; r < 4; r++) {
                const int row = m0 + wm + mt * 16 + quad * 4 + r;
                const int col = n0 + wn + nt * 16 + l16;
                float v = acc[mt][nt][r];
                if (applyTanh) v = tanhf(v);
                C[(size_t)row * N + col] = f2bf(v);
            }
}

// ---------------- wql = ql @ WV^T (32 x 1024, K=1024), fp32, split-K -------
// grid (16, 8): n0 = bx*64, k0 = by*128. 256 threads. atomicAdd partials.
// NOTE: wqlb must be zeroed AFTER the H->Hb conversion (overlay ordering).
__global__ __launch_bounds__(256) void wql_kernel(
    const float* __restrict__ ql, const float* __restrict__ WV, float* __restrict__ wql)
{
    __shared__ float4 qls[32][32];      // [c][kq]   16 KB
    __shared__ float4 WVs[64][33];      // [n][kq]+pad 33.8 KB
    const int tid = threadIdx.x;
    const int n0 = blockIdx.x * 64;
    const int k0 = blockIdx.y * 128;

    for (int i = tid; i < 1024; i += 256)
        qls[i >> 5][i & 31] = *(const float4*)(ql + (size_t)(i >> 5) * D_MODEL + k0 + (i & 31) * 4);
    for (int i = tid; i < 2048; i += 256)
        WVs[i >> 5][i & 31] = *(const float4*)(WV + (size_t)(n0 + (i >> 5)) * D_MODEL + k0 + (i & 31) * 4);
    __syncthreads();

    const int n = tid & 63;
    const int c0 = (tid >> 6) * 8;
    float acc[8] = {};
    for (int kq = 0; kq < 32; kq++) {
        const float4 wv = WVs[n][kq];
#pragma unroll
        for (int c = 0; c < 8; c++) acc[c] += dot4(qls[c0 + c][kq], wv);
    }
#pragma unroll
    for (int c = 0; c < 8; c++)
        atomicAdd(&wql[(size_t)(c0 + c) * D_MODEL + n0 + n], acc[c]);
}

// ---------------- KV via MFMA ------------------------------------------------
// kv[((b*16+z)*32 + c)*512 + t] = sum_h tanh(H[b,t,z*64+h]) * wql[c,z*64+h]
// grid (128 bt-chunks, 16 z), 256 thr = 4 waves; each wave: 2 t-tiles x 2 c-tiles.
// H fp32 loaded direct (coalesced), tanh+cvt to bf16 in LDS; LDS transpose for
// fully-coalesced float4 stores of t-rows.
__global__ __launch_bounds__(256) void kv_gemm(
    const float* __restrict__ H, const unsigned short* __restrict__ wql16,
    float* __restrict__ kv)
{
    __shared__ unsigned short Ks[128 * 64];  // 16 KB   [tl][h] bf16
    __shared__ float kvt[128 * 33];          // 16.9 KB [tl][c] padded
    const int chunk = blockIdx.x;
    const int z = blockIdx.y;
    const int b = chunk >> 2;
    const int t0 = (chunk & 3) * 128;
    const int tid = threadIdx.x;
    const int wid = tid >> 6;
    const int lane = tid & 63;
    const int quad = lane >> 4;
    const int l16 = lane & 15;

    // stage tanh(H) slice: 128 rows x 64 floats -> bf16 LDS
#pragma unroll
    for (int it = 0; it < 8; it++) {
        const int idx = it * 256 + tid;   // 0..2047 float4 units
        const int row = idx >> 4;         // 0..127
        const int c4 = (idx & 15) * 4;    // 0..60
        float4 v = *(const float4*)(H + ((size_t)b * T_LEN + t0 + row) * D_MODEL + z * D_K + c4);
        v = tanh4(v);
        ushort4 o;
        o.x = f2bf(v.x); o.y = f2bf(v.y); o.z = f2bf(v.z); o.w = f2bf(v.w);
        *(ushort4*)&Ks[row * 64 + c4] = o;
    }
    // B fragments: wql16 rows c (n-side), k = h
    bf16x8 bfr[2][2];
#pragma unroll
    for (int ct = 0; ct < 2; ct++)
#pragma unroll
        for (int kh = 0; kh < 2; kh++)
            bfr[ct][kh] = *(const bf16x8*)(wql16 +
                (size_t)(ct * 16 + l16) * D_MODEL + z * D_K + kh * 32 + quad * 8);
    __syncthreads();

    const int wt = wid * 32;
    f32x4 acc[2][2] = {};
#pragma unroll
    for (int tt = 0; tt < 2; tt++) {
        const bf16x8 a0 = *(const bf16x8*)&Ks[(wt + tt * 16 + l16) * 64 + quad * 8];
        const bf16x8 a1 = *(const bf16x8*)&Ks[(wt + tt * 16 + l16) * 64 + 32 + quad * 8];
#pragma unroll
        for (int ct = 0; ct < 2; ct++) {
            acc[tt][ct] = __builtin_amdgcn_mfma_f32_16x16x32_bf16(a0, bfr[ct][0], acc[tt][ct], 0, 0, 0);
            acc[tt][ct] = __builtin_amdgcn_mfma_f32_16x16x32_bf16(a1, bfr[ct][1], acc[tt][ct], 0, 0, 0);
        }
    }
    // C layout: row(t in tile)=quad*4+r, col(c)=l16 -> transpose via LDS
#pragma unroll
    for (int tt = 0; tt < 2; tt++)
#pragma unroll
        for (int ct = 0; ct < 2; ct++)
#pragma unroll
            for (int r = 0; r < 4; r++)
                kvt[(wt + tt * 16 + quad * 4 + r) * 33 + ct * 16 + l16] = acc[tt][ct][r];
    __syncthreads();

    float* outb = kv + (((size_t)b * 16 + z) * 32) * 512 + t0;
#pragma unroll
    for (int it = 0; it < 4; it++) {
        const int idx = it * 256 + tid;   // 0..1023 float4 units
        const int c = idx >> 5;           // 0..31
        const int tq = (idx & 31) * 4;    // 0..124
        float4 v = make_float4(kvt[(tq + 0) * 33 + c], kvt[(tq + 1) * 33 + c],
                               kvt[(tq + 2) * 33 + c], kvt[(tq + 3) * 33 + c]);
        *(float4*)(outb + (size_t)c * 512 + tq) = v;
    }
}

// ---------------- Attention via MFMA: block per (b,z), 4 waves x 8 c-tiles ---
// wkt (b,z)-slice staged to LDS via global_load_lds; kv read direct from L2.
// No max-subtraction needed: |score| <= 64 so exp() can't overflow fp32.
__global__ __launch_bounds__(256) void attn_mfma(
    const unsigned short* __restrict__ qproj, const unsigned short* __restrict__ wkt,
    const float* __restrict__ kv, float* __restrict__ out)
{
    __shared__ unsigned short wkts[512 * 64];   // 64 KB, [t][k]
    const int z = blockIdx.x;
    const int b = blockIdx.y;
    const int tid = threadIdx.x;
    const int wid = tid >> 6;
    const int lane = tid & 63;
    const int quad = lane >> 4;
    const int l16 = lane & 15;

    const unsigned short* wb = wkt + (size_t)(b * T_LEN) * D_MODEL + z * D_K;
    // stage 512 rows x 128 B = 64 KB as 4096 16B chunks (coalesced 128B/8 lanes)
#pragma unroll
    for (int it = 0; it < 16; it++) {
        const int chunk = it * 256 + tid;
        async16(&wkts[chunk * 8], wb + (size_t)(chunk >> 3) * D_MODEL + (chunk & 7) * 8);
    }

    // resident A-frags while staging is in flight
    bf16x8 af[8][2];
#pragma unroll
    for (int ct = 0; ct < 8; ct++)
#pragma unroll
        for (int kh = 0; kh < 2; kh++)
            af[ct][kh] = *(const bf16x8*)(qproj +
                (size_t)((wid * 8 + ct) * 16 + l16) * D_MODEL + z * D_K + kh * 32 + quad * 8);
    __syncthreads();

    float den[8][4], num[8][4];
#pragma unroll
    for (int ct = 0; ct < 8; ct++)
#pragma unroll
        for (int r = 0; r < 4; r++) { den[ct][r] = 0.f; num[ct][r] = 0.f; }

    // kv layout: [b][z][c][t]
    const float* kvb = kv + (((size_t)b * 16 + z) * 32) * 512;
    for (int nt = 0; nt < 32; nt++) {
        const bf16x8 b0 = *(const bf16x8*)&wkts[(nt * 16 + l16) * 64 + quad * 8];
        const bf16x8 b1 = *(const bf16x8*)&wkts[(nt * 16 + l16) * 64 + 32 + quad * 8];
#pragma unroll
        for (int ct = 0; ct < 8; ct++) {
            f32x4 a = {};
            a = __builtin_amdgcn_mfma_f32_16x16x32_bf16(af[ct][0], b0, a, 0, 0, 0);
            a = __builtin_amdgcn_mfma_f32_16x16x32_bf16(af[ct][1], b1, a, 0, 0, 0);
            const float kvv = kvb[(size_t)(wid * 8 + ct) * 512 + nt * 16 + l16];
#pragma unroll
            for (int r = 0; r < 4; r++) {
                const float e = __expf(a[r]);
                den[ct][r] += e;
                num[ct][r] += e * kvv;
            }
        }
    }

    // reduce across the 16 lanes of each quad (cols), then combine rows/quads
#pragma unroll
    for (int ct = 0; ct < 8; ct++) {
        float s = 0.f;
#pragma unroll
        for (int r = 0; r < 4; r++) {
            float d = den[ct][r], n = num[ct][r];
#pragma unroll
            for (int off = 1; off < 16; off <<= 1) {
                d += __shfl_xor(d, off, 64);
                n += __shfl_xor(n, off, 64);
            }
            s += n / d;            // per-row num/den
        }
        s += __shfl_xor(s, 16, 64);
        s += __shfl_xor(s, 32, 64);
        if (lane == 0)
            atomicAdd(&out[b * N_CLASSES + wid * 8 + ct], s * (1.0f / 16.0f));
    }
}

extern "C" void kernel_launch(void* const* d_in, const int* in_sizes, int n_in,
                              void* d_out, int out_size, void* d_ws, size_t ws_size,
                              hipStream_t stream)
{
    const float* Q  = (const float*)d_in[0];   // (32,16,1024)
    const float* H  = (const float*)d_in[1];   // (32,512,1024)
    const float* ql = (const float*)d_in[2];   // (32,1024)
    const float* WQ = (const float*)d_in[3];   // (1024,1024)
    const float* WK = (const float*)d_in[4];
    const float* WV = (const float*)d_in[5];
    float* out = (float*)d_out;                // (32,32)

    char* ws = (char*)d_ws;
    // region A (0..33.5MB): Hb first; after wkt GEMM it is dead and overlaid
    unsigned short* Hb    = (unsigned short*)(ws);                       // 33.5 MB
    unsigned short* wkt_b = (unsigned short*)(ws + (size_t)33554432);    // 33.5 MB
    float*          kv    = (float*)(ws + (size_t)67108864);             // 33.5 MB
    unsigned short* WKb   = (unsigned short*)(ws + (size_t)100663296);   // 2 MB
    // overlays into region A (used only after wkt GEMM / H conversion):
    unsigned short* Qb      = (unsigned short*)(ws);                     // 1 MB
    unsigned short* WQb     = (unsigned short*)(ws + (size_t)(1 << 20)); // 2 MB
    unsigned short* qproj_b = (unsigned short*)(ws + (size_t)(3 << 20)); // 1 MB
    float*          wqlb    = (float*)(ws + (size_t)(4 << 20));          // 128 KB
    unsigned short* wqlb16  = (unsigned short*)(ws + (size_t)4718592);   // 64 KB (4.5 MB offset)

    hipMemsetAsync(d_out, 0, (size_t)out_size * sizeof(float), stream);

    dim3 thr(256);
    // bf16 conversions for the dominant GEMM
    cvt_bf16<<<dim3(16384), thr, 0, stream>>>((const float4*)H, (ushort4*)Hb, 4194304);
    cvt_bf16<<<dim3(1024), thr, 0, stream>>>((const float4*)WK, (ushort4*)WKb, 262144);
    // wkt = tanh(H @ WK^T)  (16384 x 1024), bf16 out
    gemm_bf16_bt<<<dim3(8, 128), thr, 0, stream>>>(Hb, WKb, wkt_b, 16384, 1024, 1024, 1);
    // Hb dead -> overlay region A
    cvt_bf16<<<dim3(512), thr, 0, stream>>>((const float4*)Q, (ushort4*)Qb, 131072);
    cvt_bf16<<<dim3(1024), thr, 0, stream>>>((const float4*)WQ, (ushort4*)WQb, 262144);
    // qproj = Q @ WQ^T  (512 x 1024), bf16 out
    gemm_bf16_bt<<<dim3(8, 4), thr, 0, stream>>>(Qb, WQb, qproj_b, 512, 1024, 1024, 0);
    // zero wqlb ONLY NOW (cvt_bf16(H->Hb) above writes through this region)
    hipMemsetAsync(wqlb, 0, (size_t)N_CLASSES * D_MODEL * sizeof(float), stream);
    // Wql = ql @ WV^T  (32 x 1024), fp32 split-K
    wql_kernel<<<dim3(16, 8), thr, 0, stream>>>(ql, WV, wqlb);
    // wql -> bf16 for the kv MFMA
    cvt_bf16<<<dim3(32), thr, 0, stream>>>((const float4*)wqlb, (ushort4*)wqlb16, 8192);
    // kv(b,z,c,t) via MFMA (was the 84 us latency-bound kv_kernel)
    kv_gemm<<<dim3(128, 16), thr, 0, stream>>>(H, wqlb16, kv);
    // fused scores -> softmax -> dot(kv) -> mean_s, atomic over z
    attn_mfma<<<dim3(16, 32), thr, 0, stream>>>(qproj_b, wkt_b, kv, out);
}

// Round 6
// 281.654 us; speedup vs baseline: 5.0296x; 1.0467x over previous
//
#include <hip/hip_runtime.h>
#include <hip/hip_bf16.h>
#include <math.h>

#define D_MODEL 1024
#define N_HEADS 16
#define D_K 64
#define N_CLASSES 32
#define S_LEN 16
#define BATCH 32
#define T_LEN 512

typedef __bf16 bf16_t;
typedef bf16_t bf16x8 __attribute__((ext_vector_type(8)));
typedef float f32x4 __attribute__((ext_vector_type(4)));

__device__ inline unsigned short f2bf(float f) {
    unsigned int u = __float_as_uint(f);
    unsigned int r = (u + 0x7FFFu + ((u >> 16) & 1u)) >> 16;   // RNE
    return (unsigned short)r;
}
__device__ inline float4 tanh4(float4 v) {
    return make_float4(tanhf(v.x), tanhf(v.y), tanhf(v.z), tanhf(v.w));
}
__device__ inline float dot4(float4 a, float4 b) {
    return a.x * b.x + a.y * b.y + a.z * b.z + a.w * b.w;
}

// async global->LDS, 16 bytes per lane (global_load_lds_dwordx4)
__device__ inline void async16(void* lds, const void* g) {
    __builtin_amdgcn_global_load_lds(
        (const __attribute__((address_space(1))) unsigned int*)g,
        (__attribute__((address_space(3))) unsigned int*)lds, 16, 0, 0);
}

// ---------------- fp32 -> bf16 conversion, two arrays per launch ------------
__global__ __launch_bounds__(256) void cvt2_bf16(
    const float4* __restrict__ inA, ushort4* __restrict__ outA, int nA4,
    const float4* __restrict__ inB, ushort4* __restrict__ outB, int nB4)
{
    int i = blockIdx.x * 256 + threadIdx.x;
    const float4* in;
    ushort4* out;
    if (i < nA4) { in = inA + i; out = outA + i; }
    else {
        i -= nA4;
        if (i >= nB4) return;
        in = inB + i; out = outB + i;
    }
    float4 v = *in;
    ushort4 o;
    o.x = f2bf(v.x); o.y = f2bf(v.y); o.z = f2bf(v.z); o.w = f2bf(v.w);
    *out = o;
}

__global__ __launch_bounds__(256) void cvt_bf16(
    const float4* __restrict__ in, ushort4* __restrict__ out, int n4)
{
    int i = blockIdx.x * 256 + threadIdx.x;
    if (i < n4) {
        float4 v = in[i];
        ushort4 o;
        o.x = f2bf(v.x); o.y = f2bf(v.y); o.z = f2bf(v.z); o.w = f2bf(v.w);
        out[i] = o;
    }
}

// ---------------- bf16 MFMA GEMM: C = op(A @ B^T), bf16 out ----------------
// A: (M,K) bf16 row-major, B: (N,K) bf16 row-major, C: (M,N) bf16 row-major.
// 128x128 tile, BK=32, 256 thr = 4 waves (2x2 of 64x64), 4x4 acc of 16x16x32.
// GRID: x = m (fast), y = n. m-fast => the 8 n-blocks of one m-row share an
// XCD (id % 8 == bx % 8), so the A-tile is served from that XCD's L2 instead
// of being re-fetched from HBM by every XCD (round-5: 133 MB fetch vs 36 ideal).
__global__ __launch_bounds__(256) void gemm_bf16_bt(
    const unsigned short* __restrict__ A, const unsigned short* __restrict__ B,
    unsigned short* __restrict__ C, int M, int N, int K, int applyTanh)
{
    __shared__ unsigned short As[128 * 32];   // 8 KB
    __shared__ unsigned short Bs[128 * 32];   // 8 KB
    const int tid = threadIdx.x;
    const int m0 = blockIdx.x * 128;
    const int n0 = blockIdx.y * 128;
    const int wid = tid >> 6;
    const int lane = tid & 63;
    const int quad = lane >> 4;
    const int l16 = lane & 15;
    const int wm = (wid >> 1) * 64;
    const int wn = (wid & 1) * 64;

    f32x4 acc[4][4] = {};

    const int r0 = tid >> 2;          // staging row 0..63
    const int cc0 = (tid & 3) * 8;    // k-offset within 32 (elements)

    for (int k0 = 0; k0 < K; k0 += 32) {
        async16(&As[tid * 8],        A + (size_t)(m0 + r0) * K + k0 + cc0);
        async16(&As[2048 + tid * 8], A + (size_t)(m0 + 64 + r0) * K + k0 + cc0);
        async16(&Bs[tid * 8],        B + (size_t)(n0 + r0) * K + k0 + cc0);
        async16(&Bs[2048 + tid * 8], B + (size_t)(n0 + 64 + r0) * K + k0 + cc0);
        __syncthreads();

        bf16x8 af[4], bfr[4];
#pragma unroll
        for (int mt = 0; mt < 4; mt++)
            af[mt] = *(const bf16x8*)&As[(wm + mt * 16 + l16) * 32 + quad * 8];
#pragma unroll
        for (int nt = 0; nt < 4; nt++)
            bfr[nt] = *(const bf16x8*)&Bs[(wn + nt * 16 + l16) * 32 + quad * 8];
#pragma unroll
        for (int mt = 0; mt < 4; mt++)
#pragma unroll
            for (int nt = 0; nt < 4; nt++)
                acc[mt][nt] = __builtin_amdgcn_mfma_f32_16x16x32_bf16(
                    af[mt], bfr[nt], acc[mt][nt], 0, 0, 0);
        __syncthreads();
    }

#pragma unroll
    for (int mt = 0; mt < 4; mt++)
#pragma unroll
        for (int nt = 0; nt < 4; nt++)
#pragma unroll
            for (int r = 0; r < 4; r++) {
                const int row = m0 + wm + mt * 16 + quad * 4 + r;
                const int col = n0 + wn + nt * 16 + l16;
                float v = acc[mt][nt][r];
                if (applyTanh) v = tanhf(v);
                C[(size_t)row * N + col] = f2bf(v);
            }
}

// ---------------- wql = ql @ WV^T (32 x 1024, K=1024), fp32, split-K -------
// grid (16, 8): n0 = bx*64, k0 = by*128. 256 threads. atomicAdd partials.
// NOTE: wqlb must be zeroed AFTER the H->Hb conversion (overlay ordering).
__global__ __launch_bounds__(256) void wql_kernel(
    const float* __restrict__ ql, const float* __restrict__ WV, float* __restrict__ wql)
{
    __shared__ float4 qls[32][32];      // [c][kq]   16 KB
    __shared__ float4 WVs[64][33];      // [n][kq]+pad 33.8 KB
    const int tid = threadIdx.x;
    const int n0 = blockIdx.x * 64;
    const int k0 = blockIdx.y * 128;

    for (int i = tid; i < 1024; i += 256)
        qls[i >> 5][i & 31] = *(const float4*)(ql + (size_t)(i >> 5) * D_MODEL + k0 + (i & 31) * 4);
    for (int i = tid; i < 2048; i += 256)
        WVs[i >> 5][i & 31] = *(const float4*)(WV + (size_t)(n0 + (i >> 5)) * D_MODEL + k0 + (i & 31) * 4);
    __syncthreads();

    const int n = tid & 63;
    const int c0 = (tid >> 6) * 8;
    float acc[8] = {};
    for (int kq = 0; kq < 32; kq++) {
        const float4 wv = WVs[n][kq];
#pragma unroll
        for (int c = 0; c < 8; c++) acc[c] += dot4(qls[c0 + c][kq], wv);
    }
#pragma unroll
    for (int c = 0; c < 8; c++)
        atomicAdd(&wql[(size_t)(c0 + c) * D_MODEL + n0 + n], acc[c]);
}

// ---------------- KV via MFMA ------------------------------------------------
// kv[((b*16+z)*32 + c)*512 + t] = sum_h tanh(H[b,t,z*64+h]) * wql[c,z*64+h]
// grid (128 bt-chunks, 16 z), 256 thr = 4 waves; each wave: 2 t-tiles x 2 c-tiles.
__global__ __launch_bounds__(256) void kv_gemm(
    const float* __restrict__ H, const unsigned short* __restrict__ wql16,
    float* __restrict__ kv)
{
    __shared__ unsigned short Ks[128 * 64];  // 16 KB   [tl][h] bf16
    __shared__ float kvt[128 * 33];          // 16.9 KB [tl][c] padded
    const int chunk = blockIdx.x;
    const int z = blockIdx.y;
    const int b = chunk >> 2;
    const int t0 = (chunk & 3) * 128;
    const int tid = threadIdx.x;
    const int wid = tid >> 6;
    const int lane = tid & 63;
    const int quad = lane >> 4;
    const int l16 = lane & 15;

    // stage tanh(H) slice: 128 rows x 64 floats -> bf16 LDS
#pragma unroll
    for (int it = 0; it < 8; it++) {
        const int idx = it * 256 + tid;   // 0..2047 float4 units
        const int row = idx >> 4;         // 0..127
        const int c4 = (idx & 15) * 4;    // 0..60
        float4 v = *(const float4*)(H + ((size_t)b * T_LEN + t0 + row) * D_MODEL + z * D_K + c4);
        v = tanh4(v);
        ushort4 o;
        o.x = f2bf(v.x); o.y = f2bf(v.y); o.z = f2bf(v.z); o.w = f2bf(v.w);
        *(ushort4*)&Ks[row * 64 + c4] = o;
    }
    // B fragments: wql16 rows c (n-side), k = h
    bf16x8 bfr[2][2];
#pragma unroll
    for (int ct = 0; ct < 2; ct++)
#pragma unroll
        for (int kh = 0; kh < 2; kh++)
            bfr[ct][kh] = *(const bf16x8*)(wql16 +
                (size_t)(ct * 16 + l16) * D_MODEL + z * D_K + kh * 32 + quad * 8);
    __syncthreads();

    const int wt = wid * 32;
    f32x4 acc[2][2] = {};
#pragma unroll
    for (int tt = 0; tt < 2; tt++) {
        const bf16x8 a0 = *(const bf16x8*)&Ks[(wt + tt * 16 + l16) * 64 + quad * 8];
        const bf16x8 a1 = *(const bf16x8*)&Ks[(wt + tt * 16 + l16) * 64 + 32 + quad * 8];
#pragma unroll
        for (int ct = 0; ct < 2; ct++) {
            acc[tt][ct] = __builtin_amdgcn_mfma_f32_16x16x32_bf16(a0, bfr[ct][0], acc[tt][ct], 0, 0, 0);
            acc[tt][ct] = __builtin_amdgcn_mfma_f32_16x16x32_bf16(a1, bfr[ct][1], acc[tt][ct], 0, 0, 0);
        }
    }
    // C layout: row(t in tile)=quad*4+r, col(c)=l16 -> transpose via LDS
#pragma unroll
    for (int tt = 0; tt < 2; tt++)
#pragma unroll
        for (int ct = 0; ct < 2; ct++)
#pragma unroll
            for (int r = 0; r < 4; r++)
                kvt[(wt + tt * 16 + quad * 4 + r) * 33 + ct * 16 + l16] = acc[tt][ct][r];
    __syncthreads();

    float* outb = kv + (((size_t)b * 16 + z) * 32) * 512 + t0;
#pragma unroll
    for (int it = 0; it < 4; it++) {
        const int idx = it * 256 + tid;   // 0..1023 float4 units
        const int c = idx >> 5;           // 0..31
        const int tq = (idx & 31) * 4;    // 0..124
        float4 v = make_float4(kvt[(tq + 0) * 33 + c], kvt[(tq + 1) * 33 + c],
                               kvt[(tq + 2) * 33 + c], kvt[(tq + 3) * 33 + c]);
        *(float4*)(outb + (size_t)c * 512 + tq) = v;
    }
}

// ---------------- Attention via MFMA: block per (b,z), 4 waves x 8 c-tiles ---
// wkt (b,z)-slice staged to LDS via global_load_lds; kv read direct from L2.
// No max-subtraction needed: |score| <= 64 so exp() can't overflow fp32.
__global__ __launch_bounds__(256) void attn_mfma(
    const unsigned short* __restrict__ qproj, const unsigned short* __restrict__ wkt,
    const float* __restrict__ kv, float* __restrict__ out)
{
    __shared__ unsigned short wkts[512 * 64];   // 64 KB, [t][k]
    const int z = blockIdx.x;
    const int b = blockIdx.y;
    const int tid = threadIdx.x;
    const int wid = tid >> 6;
    const int lane = tid & 63;
    const int quad = lane >> 4;
    const int l16 = lane & 15;

    const unsigned short* wb = wkt + (size_t)(b * T_LEN) * D_MODEL + z * D_K;
    // stage 512 rows x 128 B = 64 KB as 4096 16B chunks (coalesced 128B/8 lanes)
#pragma unroll
    for (int it = 0; it < 16; it++) {
        const int chunk = it * 256 + tid;
        async16(&wkts[chunk * 8], wb + (size_t)(chunk >> 3) * D_MODEL + (chunk & 7) * 8);
    }

    // resident A-frags while staging is in flight
    bf16x8 af[8][2];
#pragma unroll
    for (int ct = 0; ct < 8; ct++)
#pragma unroll
        for (int kh = 0; kh < 2; kh++)
            af[ct][kh] = *(const bf16x8*)(qproj +
                (size_t)((wid * 8 + ct) * 16 + l16) * D_MODEL + z * D_K + kh * 32 + quad * 8);
    __syncthreads();

    float den[8][4], num[8][4];
#pragma unroll
    for (int ct = 0; ct < 8; ct++)
#pragma unroll
        for (int r = 0; r < 4; r++) { den[ct][r] = 0.f; num[ct][r] = 0.f; }

    // kv layout: [b][z][c][t]
    const float* kvb = kv + (((size_t)b * 16 + z) * 32) * 512;
    for (int nt = 0; nt < 32; nt++) {
        const bf16x8 b0 = *(const bf16x8*)&wkts[(nt * 16 + l16) * 64 + quad * 8];
        const bf16x8 b1 = *(const bf16x8*)&wkts[(nt * 16 + l16) * 64 + 32 + quad * 8];
#pragma unroll
        for (int ct = 0; ct < 8; ct++) {
            f32x4 a = {};
            a = __builtin_amdgcn_mfma_f32_16x16x32_bf16(af[ct][0], b0, a, 0, 0, 0);
            a = __builtin_amdgcn_mfma_f32_16x16x32_bf16(af[ct][1], b1, a, 0, 0, 0);
            const float kvv = kvb[(size_t)(wid * 8 + ct) * 512 + nt * 16 + l16];
#pragma unroll
            for (int r = 0; r < 4; r++) {
                const float e = __expf(a[r]);
                den[ct][r] += e;
                num[ct][r] += e * kvv;
            }
        }
    }

    // reduce across the 16 lanes of each quad (cols), then combine rows/quads
#pragma unroll
    for (int ct = 0; ct < 8; ct++) {
        float s = 0.f;
#pragma unroll
        for (int r = 0; r < 4; r++) {
            float d = den[ct][r], n = num[ct][r];
#pragma unroll
            for (int off = 1; off < 16; off <<= 1) {
                d += __shfl_xor(d, off, 64);
                n += __shfl_xor(n, off, 64);
            }
            s += n / d;            // per-row num/den
        }
        s += __shfl_xor(s, 16, 64);
        s += __shfl_xor(s, 32, 64);
        if (lane == 0)
            atomicAdd(&out[b * N_CLASSES + wid * 8 + ct], s * (1.0f / 16.0f));
    }
}

extern "C" void kernel_launch(void* const* d_in, const int* in_sizes, int n_in,
                              void* d_out, int out_size, void* d_ws, size_t ws_size,
                              hipStream_t stream)
{
    const float* Q  = (const float*)d_in[0];   // (32,16,1024)
    const float* H  = (const float*)d_in[1];   // (32,512,1024)
    const float* ql = (const float*)d_in[2];   // (32,1024)
    const float* WQ = (const float*)d_in[3];   // (1024,1024)
    const float* WK = (const float*)d_in[4];
    const float* WV = (const float*)d_in[5];
    float* out = (float*)d_out;                // (32,32)

    char* ws = (char*)d_ws;
    // region A (0..33.5MB): Hb first; after wkt GEMM it is dead and overlaid
    unsigned short* Hb    = (unsigned short*)(ws);                       // 33.5 MB
    unsigned short* wkt_b = (unsigned short*)(ws + (size_t)33554432);    // 33.5 MB
    float*          kv    = (float*)(ws + (size_t)67108864);             // 33.5 MB
    unsigned short* WKb   = (unsigned short*)(ws + (size_t)100663296);   // 2 MB
    // overlays into region A (used only after wkt GEMM / H conversion):
    unsigned short* Qb      = (unsigned short*)(ws);                     // 1 MB
    unsigned short* WQb     = (unsigned short*)(ws + (size_t)(1 << 20)); // 2 MB
    unsigned short* qproj_b = (unsigned short*)(ws + (size_t)(3 << 20)); // 1 MB
    float*          wqlb    = (float*)(ws + (size_t)(4 << 20));          // 128 KB
    unsigned short* wqlb16  = (unsigned short*)(ws + (size_t)4718592);   // 64 KB (4.5 MB offset)

    hipMemsetAsync(d_out, 0, (size_t)out_size * sizeof(float), stream);

    dim3 thr(256);
    // bf16 conversions for the dominant GEMM (H + WK in one launch)
    cvt2_bf16<<<dim3(17408), thr, 0, stream>>>(
        (const float4*)H, (ushort4*)Hb, 4194304,
        (const float4*)WK, (ushort4*)WKb, 262144);
    // wkt = tanh(H @ WK^T)  (16384 x 1024), bf16 out. Grid: m fast (XCD reuse).
    gemm_bf16_bt<<<dim3(128, 8), thr, 0, stream>>>(Hb, WKb, wkt_b, 16384, 1024, 1024, 1);
    // Hb dead -> overlay region A (Q + WQ in one launch)
    cvt2_bf16<<<dim3(1536), thr, 0, stream>>>(
        (const float4*)Q, (ushort4*)Qb, 131072,
        (const float4*)WQ, (ushort4*)WQb, 262144);
    // qproj = Q @ WQ^T  (512 x 1024), bf16 out
    gemm_bf16_bt<<<dim3(4, 8), thr, 0, stream>>>(Qb, WQb, qproj_b, 512, 1024, 1024, 0);
    // zero wqlb ONLY NOW (cvt2(H) above writes through this region)
    hipMemsetAsync(wqlb, 0, (size_t)N_CLASSES * D_MODEL * sizeof(float), stream);
    // Wql = ql @ WV^T  (32 x 1024), fp32 split-K
    wql_kernel<<<dim3(16, 8), thr, 0, stream>>>(ql, WV, wqlb);
    // wql -> bf16 for the kv MFMA
    cvt_bf16<<<dim3(32), thr, 0, stream>>>((const float4*)wqlb, (ushort4*)wqlb16, 8192);
    // kv(b,z,c,t) via MFMA
    kv_gemm<<<dim3(128, 16), thr, 0, stream>>>(H, wqlb16, kv);
    // fused scores -> softmax -> dot(kv) -> mean_s, atomic over z
    attn_mfma<<<dim3(16, 32), thr, 0, stream>>>(qproj_b, wkt_b, kv, out);
}